// Round 8
// baseline (334.286 us; speedup 1.0000x reference)
//
#include <hip/hip_runtime.h>
#include <stdint.h>

#define D_IN 256
#define D_OUT 128
#define MAXB 800     // max dst-buckets of 128 nodes (N <= 102400)
#define NCHUNK 256   // edge chunks (blocks) for partition passes

typedef __attribute__((ext_vector_type(8))) short bf16x8;
typedef __attribute__((ext_vector_type(4))) float f32x4;

__device__ __forceinline__ unsigned short f2bf(float f) {
  union { float f; uint32_t u; } v; v.f = f;
  uint32_t u = v.u;
  uint32_t r = (u + 0x7FFFu + ((u >> 16) & 1u)) >> 16;  // RNE
  return (unsigned short)r;
}
__device__ __forceinline__ float bf_lo(uint32_t u) {
  union { uint32_t u; float f; } v; v.u = u << 16; return v.f;
}
__device__ __forceinline__ float bf_hi(uint32_t u) {
  union { uint32_t u; float f; } v; v.u = u & 0xFFFF0000u; return v.f;
}
// First/second half of a uint4 of 8 packed bf16 -> f32x4 (vector adds -> pk_add).
__device__ __forceinline__ f32x4 bq_a(uint4 u) {
  return f32x4{bf_lo(u.x), bf_hi(u.x), bf_lo(u.y), bf_hi(u.y)};
}
__device__ __forceinline__ f32x4 bq_b(uint4 u) {
  return f32x4{bf_lo(u.z), bf_hi(u.z), bf_lo(u.w), bf_hi(u.w)};
}

// Async global->LDS DMA, 16B per lane. LDS dest is wave-uniform base + lane*16
// (HW rule); global src is per-lane.
__device__ __forceinline__ void dma16(const float* gsrc, float* ldst) {
  __builtin_amdgcn_global_load_lds(
      (const __attribute__((address_space(1))) void*)gsrc,
      (__attribute__((address_space(3))) void*)ldst, 16, 0, 0);
}

// W[k][n] (256x128 fp32) -> WT[n][k] (128x256 bf16): B-fragments 16B-contiguous.
__global__ __launch_bounds__(256) void k_conv_w(const float* __restrict__ W,
                                                unsigned short* __restrict__ wt) {
  int idx = blockIdx.x * 256 + threadIdx.x;  // 32768
  int n = idx >> 8;
  int k = idx & 255;
  wt[idx] = f2bf(W[k * D_OUT + n]);
}

// h' = dinv .* (x@W), MFMA 16x16x32 bf16. Column-split + global_load_lds DMA
// double-buffered staging (round-5 verified). PRE-SCALE by dinv[row].
// Round-8: output written in SHARD-PLANE layout hps[s][row][16 cols] bf16
// (plane = N*32 B = 3.2 MB, fits one XCD's 4 MB L2). Wave w owns cols
// [w*16,(w+1)*16) = exactly shard w -> one-line address change; per-tile wave
// writes become 512 B contiguous (16 rows x 32 B).
// Swizzle (rule #21, both-sides-or-neither): 16B-granule XOR g^=(row&7) on the
// per-lane GLOBAL source (LDS dest linear, HW rule) and on the LDS read addr.
__global__ __launch_bounds__(512) void k_gemm(const float* __restrict__ x,
                                              const unsigned short* __restrict__ wt,
                                              const float* __restrict__ dinv,
                                              unsigned short* __restrict__ hp, int N) {
  __shared__ float xl[2][16][256];  // 32 KB double buffer, granule-swizzled

  int wave = threadIdx.x >> 6;
  int lane = threadIdx.x & 63;
  int m = lane & 15;
  int q = lane >> 4;

  // Loop-invariant B fragments: col = wave*16 + m, k = q*8 + kt*32 + j.
  bf16x8 bw[8];
  const unsigned short* wrow = wt + (size_t)(wave * 16 + m) * D_IN + q * 8;
#pragma unroll
  for (int kt = 0; kt < 8; ++kt)
    bw[kt] = *reinterpret_cast<const bf16x8*>(wrow + kt * 32);

  int tiles = (N + 15) >> 4;  // N % 16 == 0
  int ipb = (tiles + gridDim.x - 1) / gridDim.x;
  int t0 = blockIdx.x * ipb;
  int tend = t0 + ipb;
  if (tend > tiles) tend = tiles;
  if (t0 >= tend) return;

  // Stage one 16-row tile: 1 KB DMA per row, 2 rows per wave (r = wave, wave+8).
  // Lane l fetches global granule l^(r&7) into linear LDS granule l.
  auto stage_tile = [&](int buf, int tt) {
#pragma unroll
    for (int rr = 0; rr < 2; ++rr) {
      int r = wave + rr * 8;
      const float* gsrc = x + ((size_t)tt * 16 + r) * D_IN + ((lane ^ (r & 7)) << 2);
      dma16(gsrc, &xl[buf][r][0]);
    }
  };

  stage_tile(0, t0);
  __syncthreads();

  int cur = 0;
  int sw = m & 7;
  unsigned short* hpw = hp + (size_t)wave * N * 16;  // this wave's shard plane

  for (int t = t0; t < tend; ++t) {
    if (t + 1 < tend) stage_tile(cur ^ 1, t + 1);

    const float* prow = &xl[cur][m][0];
    f32x4 acc = {0.f, 0.f, 0.f, 0.f};
#pragma unroll
    for (int kt = 0; kt < 8; ++kt) {
      int g0 = q * 2 + kt * 8;  // 16B granule within row (pre-swizzle)
      float4 u0 = *reinterpret_cast<const float4*>(prow + ((g0 ^ sw) << 2));
      float4 u1 = *reinterpret_cast<const float4*>(prow + (((g0 + 1) ^ sw) << 2));
      bf16x8 av;
      av[0] = (short)f2bf(u0.x); av[1] = (short)f2bf(u0.y);
      av[2] = (short)f2bf(u0.z); av[3] = (short)f2bf(u0.w);
      av[4] = (short)f2bf(u1.x); av[5] = (short)f2bf(u1.y);
      av[6] = (short)f2bf(u1.z); av[7] = (short)f2bf(u1.w);
      acc = __builtin_amdgcn_mfma_f32_16x16x32_bf16(av, bw[kt], acc, 0, 0, 0);
    }

    int r0 = t * 16;
#pragma unroll
    for (int r = 0; r < 4; ++r) {
      int row = r0 + q * 4 + r;
      hpw[(size_t)row * 16 + m] = f2bf(dinv[row] * acc[r]);
    }

    __syncthreads();  // drains DMA (vmcnt) + orders all waves' LDS reads
    cur ^= 1;
  }
}

// passA: per-chunk LDS histogram over dst-buckets -> cntm[b][c]. LDS atomics only.
__global__ __launch_bounds__(256) void k_passA(const int* __restrict__ ei, int E, int CH,
                                               int NB, int* __restrict__ cntm) {
  __shared__ int bins[MAXB];
  int c = blockIdx.x;
  for (int b = threadIdx.x; b < NB; b += 256) bins[b] = 0;
  __syncthreads();
  int start = c * CH, end = min(E, start + CH);
  for (int eb = start + (int)threadIdx.x * 4; eb < end; eb += 1024) {
    int kmax = end - eb; if (kmax > 4) kmax = 4;
    if (kmax == 4) {
      int4 v = *reinterpret_cast<const int4*>(ei + E + eb);
      atomicAdd(&bins[v.x >> 7], 1);
      atomicAdd(&bins[v.y >> 7], 1);
      atomicAdd(&bins[v.z >> 7], 1);
      atomicAdd(&bins[v.w >> 7], 1);
    } else {
      for (int k = 0; k < kmax; ++k) atomicAdd(&bins[ei[E + eb + k] >> 7], 1);
    }
  }
  __syncthreads();
  for (int b = threadIdx.x; b < NB; b += 256) cntm[(size_t)b * NCHUNK + c] = bins[b];
}

// scanB1: per bucket, exclusive scan of its NCHUNK chunk counts -> ofs, tot.
__global__ __launch_bounds__(NCHUNK) void k_scanB1(const int* __restrict__ cntm,
                                                   int* __restrict__ ofs,
                                                   int* __restrict__ tot) {
  __shared__ int sc[NCHUNK];
  int b = blockIdx.x, t = threadIdx.x;
  int v = cntm[(size_t)b * NCHUNK + t];
  sc[t] = v;
  __syncthreads();
  for (int off = 1; off < NCHUNK; off <<= 1) {
    int val = (t >= off) ? sc[t - off] : 0;
    __syncthreads();
    sc[t] += val;
    __syncthreads();
  }
  ofs[(size_t)b * NCHUNK + t] = sc[t] - v;
  if (t == NCHUNK - 1) tot[b] = sc[t];
}

// scanB2: single block, exclusive scan of bucket totals -> base[b]. Also nptr[N]=E.
__global__ __launch_bounds__(256) void k_scanB2(const int* __restrict__ tot,
                                                int* __restrict__ base, int NB,
                                                int* __restrict__ nptr, int N, int E) {
  __shared__ int sc[256];
  int t = threadIdx.x;
  int v[4];
  int s = 0;
#pragma unroll
  for (int j = 0; j < 4; ++j) {
    int i = t * 4 + j;
    v[j] = (i < NB) ? tot[i] : 0;
    s += v[j];
  }
  sc[t] = s;
  __syncthreads();
  for (int off = 1; off < 256; off <<= 1) {
    int val = (t >= off) ? sc[t - off] : 0;
    __syncthreads();
    sc[t] += val;
    __syncthreads();
  }
  int ex = sc[t] - s;
#pragma unroll
  for (int j = 0; j < 4; ++j) {
    int i = t * 4 + j;
    if (i < NB) base[i] = ex;
    ex += v[j];
  }
  if (t == 0) nptr[N] = E;
}

// passC: place each edge in its bucket's span. LDS cursors only.
// P entry = src | (dst&127)<<17   (src < 2^17)
__global__ __launch_bounds__(256) void k_passC(const int* __restrict__ ei, int E, int CH,
                                               int NB, const int* __restrict__ ofs,
                                               const int* __restrict__ base,
                                               int* __restrict__ P) {
  __shared__ int cur[MAXB];
  int c = blockIdx.x;
  for (int b = threadIdx.x; b < NB; b += 256)
    cur[b] = base[b] + ofs[(size_t)b * NCHUNK + c];
  __syncthreads();
  int start = c * CH, end = min(E, start + CH);
  for (int eb = start + (int)threadIdx.x * 4; eb < end; eb += 1024) {
    int kmax = end - eb; if (kmax > 4) kmax = 4;
    int s4[4], d4[4];
    if (kmax == 4) {
      int4 vs = *reinterpret_cast<const int4*>(ei + eb);
      int4 vd = *reinterpret_cast<const int4*>(ei + E + eb);
      s4[0] = vs.x; s4[1] = vs.y; s4[2] = vs.z; s4[3] = vs.w;
      d4[0] = vd.x; d4[1] = vd.y; d4[2] = vd.z; d4[3] = vd.w;
    } else {
      for (int k = 0; k < kmax; ++k) { s4[k] = ei[eb + k]; d4[k] = ei[E + eb + k]; }
    }
#pragma unroll
    for (int k = 0; k < 4; ++k) {
      if (k >= kmax) break;
      int d = d4[k];
      int p = atomicAdd(&cur[d >> 7], 1);
      P[p] = s4[k] | ((d & 127) << 17);
    }
  }
}

// sortd: per bucket counting-sort by dst-low -> P2 (globally dst-sorted CSR),
// nptr[node], dinv[node]. LDS only; no global atomics.
__global__ __launch_bounds__(256) void k_sortd(const int* __restrict__ P,
                                               const int* __restrict__ base,
                                               const int* __restrict__ tot,
                                               int* __restrict__ nptr,
                                               float* __restrict__ dinv,
                                               int* __restrict__ P2, int N) {
  __shared__ int ideg[128];
  __shared__ int sc[128];
  __shared__ int cur[128];
  int b = blockIdx.x, t = threadIdx.x;
  if (t < 128) ideg[t] = 0;
  __syncthreads();
  int s0 = base[b], T = tot[b];
  for (int i = s0 + t; i < s0 + T; i += 256) atomicAdd(&ideg[P[i] >> 17], 1);
  __syncthreads();
  if (t < 128) sc[t] = ideg[t];
  __syncthreads();
  for (int off = 1; off < 128; off <<= 1) {
    int v = (t < 128 && t >= off) ? sc[t - off] : 0;
    __syncthreads();
    if (t < 128) sc[t] += v;
    __syncthreads();
  }
  if (t < 128) {
    int exc = s0 + sc[t] - ideg[t];
    int node = b * 128 + t;
    if (node < N) {
      nptr[node] = exc;
      dinv[node] = rsqrtf(1.0f + (float)ideg[t]);
    }
    cur[t] = exc;
  }
  __syncthreads();
  for (int i = s0 + t; i < s0 + T; i += 256) {
    int pk = P[i];
    int p = atomicAdd(&cur[pk >> 17], 1);
    P2[p] = pk & 0x1FFFF;
  }
}

// agg: SHARD-PLANE gather (round 8). blockIdx = g*8 + s: shard s = bid&7 lands
// on XCD s via the round-robin dispatch -> each XCD's L2 caches ONE 3.2 MB
// plane (N x 32 B) -> gather becomes L2-resident (round-7 counters: 192 MB
// L2-miss at 2.9 TB/s fabric = the wall; unroll x4 was null at 70% occupancy).
// Wave = 4 nodes x 8 edge slots x 2 granule-lanes: 32 gathers in flight,
// 3-level shfl reduce. Epilogue: lanes j==0 write this shard's 16 fp32 cols.
__global__ __launch_bounds__(256) void k_agg(const int* __restrict__ P2,
                                             const int* __restrict__ nptr,
                                             const uint4* __restrict__ hpq,
                                             const float* __restrict__ dinv,
                                             const float* __restrict__ bias,
                                             float* __restrict__ out, int N) {
  int wave = threadIdx.x >> 6, lane = threadIdx.x & 63;
  int s = blockIdx.x & 7;   // column shard (16 cols = 32 B) -> XCD affinity
  int g = blockIdx.x >> 3;
  int nsub = lane >> 4;     // 4 nodes per wave
  int j = (lane >> 1) & 7;  // 8 edge slots
  int c = lane & 1;         // 2 x 16B granules of the 32B shard row
  int node = g * 16 + wave * 4 + nsub;
  const uint4* plane = hpq + (size_t)s * N * 2;  // plane rows: 2 granules each

  f32x4 acc0 = {0.f, 0.f, 0.f, 0.f};
  f32x4 acc1 = {0.f, 0.f, 0.f, 0.f};
  int rs = 0, re = 0;
  if (node < N) { rs = nptr[node]; re = nptr[node + 1]; }

  for (int e = rs + j; e < re; e += 8) {
    int src = P2[e];
    uint4 u = plane[(size_t)src * 2 + c];
    acc0 += bq_a(u);
    acc1 += bq_b(u);
  }

  float acc[8] = {acc0[0], acc0[1], acc0[2], acc0[3],
                  acc1[0], acc1[1], acc1[2], acc1[3]};
#pragma unroll
  for (int k = 0; k < 8; ++k) {
    acc[k] += __shfl_xor(acc[k], 2);
    acc[k] += __shfl_xor(acc[k], 4);
    acc[k] += __shfl_xor(acc[k], 8);
  }
  if (j == 0 && node < N) {
    float rsn = dinv[node];
    uint4 uh = plane[(size_t)node * 2 + c];  // hp'[node] shard (L2-hit)
    float self[8] = {bf_lo(uh.x), bf_hi(uh.x), bf_lo(uh.y), bf_hi(uh.y),
                     bf_lo(uh.z), bf_hi(uh.z), bf_lo(uh.w), bf_hi(uh.w)};
    int gi = s * 2 + c;  // 16B-granule index within the 128-col row
    const float4* b4 = reinterpret_cast<const float4*>(bias);
    float4 b0 = b4[gi * 2], b1 = b4[gi * 2 + 1];
    float bb[8] = {b0.x, b0.y, b0.z, b0.w, b1.x, b1.y, b1.z, b1.w};
    float o[8];
#pragma unroll
    for (int k = 0; k < 8; ++k) {
      float v = rsn * (acc[k] + self[k]) + bb[k];
      o[k] = v > 0.f ? v : 0.f;
    }
    float4* orow = reinterpret_cast<float4*>(out + (size_t)node * D_OUT + gi * 8);
    orow[0] = float4{o[0], o[1], o[2], o[3]};
    orow[1] = float4{o[4], o[5], o[6], o[7]};
  }
}

extern "C" void kernel_launch(void* const* d_in, const int* in_sizes, int n_in,
                              void* d_out, int out_size, void* d_ws, size_t ws_size,
                              hipStream_t stream) {
  const float* x = (const float*)d_in[0];
  const int* ei = (const int*)d_in[1];
  const float* W = (const float*)d_in[2];
  const float* bias = (const float*)d_in[3];
  int N = in_sizes[0] / D_IN;
  int E = in_sizes[1] / 2;
  float* out = (float*)d_out;

  int NB = (N + 127) >> 7;                          // 782 buckets
  int CH = ((E + NCHUNK - 1) / NCHUNK + 3) & ~3;    // 4-aligned for int4 loads

  // Workspace (~41 MB): wt | hp | dinv | cntm | ofs | tot | base | nptr | P | P2
  char* w = (char*)d_ws;
  size_t off = 0;
  auto alloc = [&](size_t bytes) -> void* {
    void* p = w + off;
    off = (off + bytes + 255) & ~(size_t)255;
    return p;
  };
  unsigned short* wt = (unsigned short*)alloc((size_t)D_IN * D_OUT * 2);
  unsigned short* hp = (unsigned short*)alloc((size_t)N * D_OUT * 2);
  float* dinv = (float*)alloc((size_t)N * 4);
  int* cntm = (int*)alloc((size_t)NB * NCHUNK * 4);
  int* ofs = (int*)alloc((size_t)NB * NCHUNK * 4);
  int* tot = (int*)alloc((size_t)NB * 4);
  int* base = (int*)alloc((size_t)NB * 4);
  int* nptr = (int*)alloc((size_t)(N + 1) * 4);
  int* P = (int*)alloc((size_t)E * 4);
  int* P2 = (int*)alloc((size_t)E * 4);
  (void)ws_size; (void)n_in; (void)out_size;

  int tiles = (N + 15) >> 4;
  int gblocks = tiles < 1024 ? tiles : 1024;

  // Partition chain first so dinv is ready for gemm's pre-scale epilogue.
  k_conv_w<<<(D_IN * D_OUT) / 256, 256, 0, stream>>>(W, wt);
  k_passA<<<NCHUNK, 256, 0, stream>>>(ei, E, CH, NB, cntm);
  k_scanB1<<<NB, NCHUNK, 0, stream>>>(cntm, ofs, tot);
  k_scanB2<<<1, 256, 0, stream>>>(tot, base, NB, nptr, N, E);
  k_passC<<<NCHUNK, 256, 0, stream>>>(ei, E, CH, NB, ofs, base, P);
  k_sortd<<<NB, 256, 0, stream>>>(P, base, tot, nptr, dinv, P2, N);
  k_gemm<<<gblocks, 512, 0, stream>>>(x, wt, dinv, hp, N);
  int gn = (N + 15) / 16;
  k_agg<<<gn * 8, 256, 0, stream>>>(P2, nptr, (const uint4*)hp, dinv, bias, out, N);
}

// Round 9
// 298.778 us; speedup vs baseline: 1.1188x; 1.1188x over previous
//
#include <hip/hip_runtime.h>
#include <stdint.h>

#define D_IN 256
#define D_OUT 128
#define MAXB 800     // max dst-buckets of 128 nodes (N <= 102400)
#define NCHUNK 256   // edge chunks (blocks) for partition passes

typedef __attribute__((ext_vector_type(8))) short bf16x8;
typedef __attribute__((ext_vector_type(4))) float f32x4;

__device__ __forceinline__ unsigned short f2bf(float f) {
  union { float f; uint32_t u; } v; v.f = f;
  uint32_t u = v.u;
  uint32_t r = (u + 0x7FFFu + ((u >> 16) & 1u)) >> 16;  // RNE
  return (unsigned short)r;
}
__device__ __forceinline__ float bf_lo(uint32_t u) {
  union { uint32_t u; float f; } v; v.u = u << 16; return v.f;
}
__device__ __forceinline__ float bf_hi(uint32_t u) {
  union { uint32_t u; float f; } v; v.u = u & 0xFFFF0000u; return v.f;
}

// Async global->LDS DMA, 16B per lane. LDS dest is wave-uniform base + lane*16
// (HW rule); global src is per-lane.
__device__ __forceinline__ void dma16(const float* gsrc, float* ldst) {
  __builtin_amdgcn_global_load_lds(
      (const __attribute__((address_space(1))) void*)gsrc,
      (__attribute__((address_space(3))) void*)ldst, 16, 0, 0);
}

// W[k][n] (256x128 fp32) -> WT[n][k] (128x256 bf16): B-fragments 16B-contiguous.
__global__ __launch_bounds__(256) void k_conv_w(const float* __restrict__ W,
                                                unsigned short* __restrict__ wt) {
  int idx = blockIdx.x * 256 + threadIdx.x;  // 32768
  int n = idx >> 8;
  int k = idx & 255;
  wt[idx] = f2bf(W[k * D_OUT + n]);
}

// h' = dinv .* (x@W), MFMA 16x16x32 bf16. Column-split + global_load_lds DMA
// double-buffered staging (round-5 verified). PRE-SCALE by dinv[row].
// Output layout back to row-major [N][128] (round-8 shard planes reverted:
// regression -38 us from wave divergence in agg).
// Swizzle (rule #21, both-sides-or-neither): 16B-granule XOR g^=(row&7) on the
// per-lane GLOBAL source (LDS dest linear, HW rule) and on the LDS read addr.
__global__ __launch_bounds__(512) void k_gemm(const float* __restrict__ x,
                                              const unsigned short* __restrict__ wt,
                                              const float* __restrict__ dinv,
                                              unsigned short* __restrict__ hp, int N) {
  __shared__ float xl[2][16][256];  // 32 KB double buffer, granule-swizzled

  int wave = threadIdx.x >> 6;
  int lane = threadIdx.x & 63;
  int m = lane & 15;
  int q = lane >> 4;

  // Loop-invariant B fragments: col = wave*16 + m, k = q*8 + kt*32 + j.
  bf16x8 bw[8];
  const unsigned short* wrow = wt + (size_t)(wave * 16 + m) * D_IN + q * 8;
#pragma unroll
  for (int kt = 0; kt < 8; ++kt)
    bw[kt] = *reinterpret_cast<const bf16x8*>(wrow + kt * 32);

  int tiles = (N + 15) >> 4;  // N % 16 == 0
  int ipb = (tiles + gridDim.x - 1) / gridDim.x;
  int t0 = blockIdx.x * ipb;
  int tend = t0 + ipb;
  if (tend > tiles) tend = tiles;
  if (t0 >= tend) return;

  // Stage one 16-row tile: 1 KB DMA per row, 2 rows per wave (r = wave, wave+8).
  // Lane l fetches global granule l^(r&7) into linear LDS granule l.
  auto stage_tile = [&](int buf, int tt) {
#pragma unroll
    for (int rr = 0; rr < 2; ++rr) {
      int r = wave + rr * 8;
      const float* gsrc = x + ((size_t)tt * 16 + r) * D_IN + ((lane ^ (r & 7)) << 2);
      dma16(gsrc, &xl[buf][r][0]);
    }
  };

  stage_tile(0, t0);
  __syncthreads();

  int cur = 0;
  int sw = m & 7;

  for (int t = t0; t < tend; ++t) {
    if (t + 1 < tend) stage_tile(cur ^ 1, t + 1);

    const float* prow = &xl[cur][m][0];
    f32x4 acc = {0.f, 0.f, 0.f, 0.f};
#pragma unroll
    for (int kt = 0; kt < 8; ++kt) {
      int g0 = q * 2 + kt * 8;  // 16B granule within row (pre-swizzle)
      float4 u0 = *reinterpret_cast<const float4*>(prow + ((g0 ^ sw) << 2));
      float4 u1 = *reinterpret_cast<const float4*>(prow + (((g0 + 1) ^ sw) << 2));
      bf16x8 av;
      av[0] = (short)f2bf(u0.x); av[1] = (short)f2bf(u0.y);
      av[2] = (short)f2bf(u0.z); av[3] = (short)f2bf(u0.w);
      av[4] = (short)f2bf(u1.x); av[5] = (short)f2bf(u1.y);
      av[6] = (short)f2bf(u1.z); av[7] = (short)f2bf(u1.w);
      acc = __builtin_amdgcn_mfma_f32_16x16x32_bf16(av, bw[kt], acc, 0, 0, 0);
    }

    int r0 = t * 16;
#pragma unroll
    for (int r = 0; r < 4; ++r) {
      int row = r0 + q * 4 + r;
      hp[(size_t)row * D_OUT + wave * 16 + m] = f2bf(dinv[row] * acc[r]);
    }

    __syncthreads();  // drains DMA (vmcnt) + orders all waves' LDS reads
    cur ^= 1;
  }
}

// passA: per-chunk LDS histogram over dst-buckets -> cntm[b][c]. LDS atomics only.
// Round-9: 1024 threads/block (was 256 = 4 waves/CU at 256 blocks -> latency-
// starved; now 16 waves/block).
__global__ __launch_bounds__(1024) void k_passA(const int* __restrict__ ei, int E,
                                                int CH, int NB,
                                                int* __restrict__ cntm) {
  __shared__ int bins[MAXB];
  int c = blockIdx.x;
  for (int b = threadIdx.x; b < NB; b += 1024) bins[b] = 0;
  __syncthreads();
  int start = c * CH, end = min(E, start + CH);
  for (int eb = start + (int)threadIdx.x * 4; eb < end; eb += 4096) {
    int kmax = end - eb; if (kmax > 4) kmax = 4;
    if (kmax == 4) {
      int4 v = *reinterpret_cast<const int4*>(ei + E + eb);
      atomicAdd(&bins[v.x >> 7], 1);
      atomicAdd(&bins[v.y >> 7], 1);
      atomicAdd(&bins[v.z >> 7], 1);
      atomicAdd(&bins[v.w >> 7], 1);
    } else {
      for (int k = 0; k < kmax; ++k) atomicAdd(&bins[ei[E + eb + k] >> 7], 1);
    }
  }
  __syncthreads();
  for (int b = threadIdx.x; b < NB; b += 1024) cntm[(size_t)b * NCHUNK + c] = bins[b];
}

// scanB1: per bucket, exclusive scan of its NCHUNK chunk counts -> ofs, tot.
__global__ __launch_bounds__(NCHUNK) void k_scanB1(const int* __restrict__ cntm,
                                                   int* __restrict__ ofs,
                                                   int* __restrict__ tot) {
  __shared__ int sc[NCHUNK];
  int b = blockIdx.x, t = threadIdx.x;
  int v = cntm[(size_t)b * NCHUNK + t];
  sc[t] = v;
  __syncthreads();
  for (int off = 1; off < NCHUNK; off <<= 1) {
    int val = (t >= off) ? sc[t - off] : 0;
    __syncthreads();
    sc[t] += val;
    __syncthreads();
  }
  ofs[(size_t)b * NCHUNK + t] = sc[t] - v;
  if (t == NCHUNK - 1) tot[b] = sc[t];
}

// scanB2: single block, exclusive scan of bucket totals -> base[b]. Also nptr[N]=E.
__global__ __launch_bounds__(256) void k_scanB2(const int* __restrict__ tot,
                                                int* __restrict__ base, int NB,
                                                int* __restrict__ nptr, int N, int E) {
  __shared__ int sc[256];
  int t = threadIdx.x;
  int v[4];
  int s = 0;
#pragma unroll
  for (int j = 0; j < 4; ++j) {
    int i = t * 4 + j;
    v[j] = (i < NB) ? tot[i] : 0;
    s += v[j];
  }
  sc[t] = s;
  __syncthreads();
  for (int off = 1; off < 256; off <<= 1) {
    int val = (t >= off) ? sc[t - off] : 0;
    __syncthreads();
    sc[t] += val;
    __syncthreads();
  }
  int ex = sc[t] - s;
#pragma unroll
  for (int j = 0; j < 4; ++j) {
    int i = t * 4 + j;
    if (i < NB) base[i] = ex;
    ex += v[j];
  }
  if (t == 0) nptr[N] = E;
}

// passC: place each edge in its bucket's span. LDS cursors only.
// P entry = src | (dst&127)<<17   (src < 2^17). Round-9: 1024 threads/block.
__global__ __launch_bounds__(1024) void k_passC(const int* __restrict__ ei, int E,
                                                int CH, int NB,
                                                const int* __restrict__ ofs,
                                                const int* __restrict__ base,
                                                int* __restrict__ P) {
  __shared__ int cur[MAXB];
  int c = blockIdx.x;
  for (int b = threadIdx.x; b < NB; b += 1024)
    cur[b] = base[b] + ofs[(size_t)b * NCHUNK + c];
  __syncthreads();
  int start = c * CH, end = min(E, start + CH);
  for (int eb = start + (int)threadIdx.x * 4; eb < end; eb += 4096) {
    int kmax = end - eb; if (kmax > 4) kmax = 4;
    int s4[4], d4[4];
    if (kmax == 4) {
      int4 vs = *reinterpret_cast<const int4*>(ei + eb);
      int4 vd = *reinterpret_cast<const int4*>(ei + E + eb);
      s4[0] = vs.x; s4[1] = vs.y; s4[2] = vs.z; s4[3] = vs.w;
      d4[0] = vd.x; d4[1] = vd.y; d4[2] = vd.z; d4[3] = vd.w;
    } else {
      for (int k = 0; k < kmax; ++k) { s4[k] = ei[eb + k]; d4[k] = ei[E + eb + k]; }
    }
#pragma unroll
    for (int k = 0; k < 4; ++k) {
      if (k >= kmax) break;
      int d = d4[k];
      int p = atomicAdd(&cur[d >> 7], 1);
      P[p] = s4[k] | ((d & 127) << 17);
    }
  }
}

// sortd: per bucket counting-sort by dst-low -> P2 (globally dst-sorted CSR),
// nptr[node], dinv[node]. LDS only; no global atomics. Round-9: 512 threads.
__global__ __launch_bounds__(512) void k_sortd(const int* __restrict__ P,
                                               const int* __restrict__ base,
                                               const int* __restrict__ tot,
                                               int* __restrict__ nptr,
                                               float* __restrict__ dinv,
                                               int* __restrict__ P2, int N) {
  __shared__ int ideg[128];
  __shared__ int sc[128];
  __shared__ int cur[128];
  int b = blockIdx.x, t = threadIdx.x;
  if (t < 128) ideg[t] = 0;
  __syncthreads();
  int s0 = base[b], T = tot[b];
  for (int i = s0 + t; i < s0 + T; i += 512) atomicAdd(&ideg[P[i] >> 17], 1);
  __syncthreads();
  if (t < 128) sc[t] = ideg[t];
  __syncthreads();
  for (int off = 1; off < 128; off <<= 1) {
    int v = (t < 128 && t >= off) ? sc[t - off] : 0;
    __syncthreads();
    if (t < 128) sc[t] += v;
    __syncthreads();
  }
  if (t < 128) {
    int exc = s0 + sc[t] - ideg[t];
    int node = b * 128 + t;
    if (node < N) {
      nptr[node] = exc;
      dinv[node] = rsqrtf(1.0f + (float)ideg[t]);
    }
    cur[t] = exc;
  }
  __syncthreads();
  for (int i = s0 + t; i < s0 + T; i += 512) {
    int pk = P[i];
    int p = atomicAdd(&cur[pk >> 17], 1);
    P2[p] = pk & 0x1FFFF;
  }
}

// agg: one wave per node (round-6 body, best known: 66.9 us). hp rows
// PRE-SCALED by dinv[src] -> pure gather-accumulate, unroll x2.
// Round-9: launched as TWO half-range dispatches (n0 offset) so the rocprof
// top-5 reveals the true second-slowest kernel (each half ~34 us).
__global__ __launch_bounds__(256) void k_agg(const int* __restrict__ P2,
                                             const int* __restrict__ nptr,
                                             const uint4* __restrict__ hrows,
                                             const float* __restrict__ dinv,
                                             const float* __restrict__ bias,
                                             float* __restrict__ out, int N, int n0) {
  int wave = threadIdx.x >> 6, lane = threadIdx.x & 63;
  int node = n0 + blockIdx.x * 4 + wave;
  if (node >= N) return;
  int rs = nptr[node], re = nptr[node + 1];
  int j = lane >> 4, c = lane & 15;

  float acc[8];
#pragma unroll
  for (int k = 0; k < 8; ++k) acc[k] = 0.f;

  int e = rs + j;
  // main: pairs (e, e+4) -> two independent gathers issued back-to-back.
  for (; e + 4 < re; e += 8) {
    int s0 = P2[e];
    int s1 = P2[e + 4];
    uint4 u0 = hrows[(size_t)s0 * 16 + c];
    uint4 u1 = hrows[(size_t)s1 * 16 + c];
    acc[0] += bf_lo(u0.x) + bf_lo(u1.x);
    acc[1] += bf_hi(u0.x) + bf_hi(u1.x);
    acc[2] += bf_lo(u0.y) + bf_lo(u1.y);
    acc[3] += bf_hi(u0.y) + bf_hi(u1.y);
    acc[4] += bf_lo(u0.z) + bf_lo(u1.z);
    acc[5] += bf_hi(u0.z) + bf_hi(u1.z);
    acc[6] += bf_lo(u0.w) + bf_lo(u1.w);
    acc[7] += bf_hi(u0.w) + bf_hi(u1.w);
  }
  if (e < re) {  // at most one leftover per slot
    int s0 = P2[e];
    uint4 u0 = hrows[(size_t)s0 * 16 + c];
    acc[0] += bf_lo(u0.x); acc[1] += bf_hi(u0.x);
    acc[2] += bf_lo(u0.y); acc[3] += bf_hi(u0.y);
    acc[4] += bf_lo(u0.z); acc[5] += bf_hi(u0.z);
    acc[6] += bf_lo(u0.w); acc[7] += bf_hi(u0.w);
  }
#pragma unroll
  for (int k = 0; k < 8; ++k) {
    acc[k] += __shfl_xor(acc[k], 16);
    acc[k] += __shfl_xor(acc[k], 32);
  }
  if (j == 0) {
    float rsn = dinv[node];
    uint4 uh = hrows[(size_t)node * 16 + c];  // hp'[node] = dinv[node]*h[node]
    float self[8] = {bf_lo(uh.x), bf_hi(uh.x), bf_lo(uh.y), bf_hi(uh.y),
                     bf_lo(uh.z), bf_hi(uh.z), bf_lo(uh.w), bf_hi(uh.w)};
    const float4* b4 = reinterpret_cast<const float4*>(bias);
    float4 b0 = b4[c * 2], b1 = b4[c * 2 + 1];
    float bb[8] = {b0.x, b0.y, b0.z, b0.w, b1.x, b1.y, b1.z, b1.w};
    float o[8];
#pragma unroll
    for (int k = 0; k < 8; ++k) {
      float v = rsn * (acc[k] + self[k]) + bb[k];
      o[k] = v > 0.f ? v : 0.f;
    }
    float4* orow = reinterpret_cast<float4*>(out + (size_t)node * D_OUT + c * 8);
    orow[0] = float4{o[0], o[1], o[2], o[3]};
    orow[1] = float4{o[4], o[5], o[6], o[7]};
  }
}

extern "C" void kernel_launch(void* const* d_in, const int* in_sizes, int n_in,
                              void* d_out, int out_size, void* d_ws, size_t ws_size,
                              hipStream_t stream) {
  const float* x = (const float*)d_in[0];
  const int* ei = (const int*)d_in[1];
  const float* W = (const float*)d_in[2];
  const float* bias = (const float*)d_in[3];
  int N = in_sizes[0] / D_IN;
  int E = in_sizes[1] / 2;
  float* out = (float*)d_out;

  int NB = (N + 127) >> 7;                          // 782 buckets
  int CH = ((E + NCHUNK - 1) / NCHUNK + 3) & ~3;    // 4-aligned for int4 loads

  // Workspace (~41 MB): wt | hp | dinv | cntm | ofs | tot | base | nptr | P | P2
  char* w = (char*)d_ws;
  size_t off = 0;
  auto alloc = [&](size_t bytes) -> void* {
    void* p = w + off;
    off = (off + bytes + 255) & ~(size_t)255;
    return p;
  };
  unsigned short* wt = (unsigned short*)alloc((size_t)D_IN * D_OUT * 2);
  unsigned short* hp = (unsigned short*)alloc((size_t)N * D_OUT * 2);
  float* dinv = (float*)alloc((size_t)N * 4);
  int* cntm = (int*)alloc((size_t)NB * NCHUNK * 4);
  int* ofs = (int*)alloc((size_t)NB * NCHUNK * 4);
  int* tot = (int*)alloc((size_t)NB * 4);
  int* base = (int*)alloc((size_t)NB * 4);
  int* nptr = (int*)alloc((size_t)(N + 1) * 4);
  int* P = (int*)alloc((size_t)E * 4);
  int* P2 = (int*)alloc((size_t)E * 4);
  (void)ws_size; (void)n_in; (void)out_size;

  int tiles = (N + 15) >> 4;
  int gblocks = tiles < 1024 ? tiles : 1024;

  // Partition chain first so dinv is ready for gemm's pre-scale epilogue.
  k_conv_w<<<(D_IN * D_OUT) / 256, 256, 0, stream>>>(W, wt);
  k_passA<<<NCHUNK, 1024, 0, stream>>>(ei, E, CH, NB, cntm);
  k_scanB1<<<NB, NCHUNK, 0, stream>>>(cntm, ofs, tot);
  k_scanB2<<<1, 256, 0, stream>>>(tot, base, NB, nptr, N, E);
  k_passC<<<NCHUNK, 1024, 0, stream>>>(ei, E, CH, NB, ofs, base, P);
  k_sortd<<<NB, 512, 0, stream>>>(P, base, tot, nptr, dinv, P2, N);
  k_gemm<<<gblocks, 512, 0, stream>>>(x, wt, dinv, hp, N);

  // agg split into two half-range dispatches (profiling visibility: forces the
  // top-5 to reveal the true runner-up kernel; same total work).
  int half = ((N / 2) + 3) & ~3;  // multiple of 4
  if (half > N) half = N;
  int g1 = (half + 3) / 4;
  int g2 = (N - half + 3) / 4;
  k_agg<<<g1, 256, 0, stream>>>(P2, nptr, (const uint4*)hp, dinv, bias, out, N, 0);
  if (g2 > 0)
    k_agg<<<g2, 256, 0, stream>>>(P2, nptr, (const uint4*)hp, dinv, bias, out, N, half);
}